// Round 3
// baseline (608.052 us; speedup 1.0000x reference)
//
#include <hip/hip_runtime.h>
#include <stdint.h>

#define K_DIM 4096
#define N_DIM 4096
#define KB    32          // K / 128
#define QMAXF 127.0f

typedef int v4i __attribute__((ext_vector_type(4)));

__device__ __forceinline__ void async_copy16(void* lds, const void* gptr) {
    __builtin_amdgcn_global_load_lds(
        (__attribute__((address_space(1))) void*)gptr,
        (__attribute__((address_space(3))) void*)lds, 16, 0, 0);
}

// ---------------- activation quant: per (row, 128-block) ----------------
__global__ __launch_bounds__(256) void act_quant_kernel(
    const float* __restrict__ x, int8_t* __restrict__ xq,
    float* __restrict__ xs_t, int M)
{
    const int m = blockIdx.x;
    const int t = threadIdx.x;
    const float* xrow = x + (size_t)m * K_DIM;
    int8_t* qrow = xq + (size_t)m * K_DIM;

#pragma unroll
    for (int p = 0; p < 4; ++p) {
        const int base = p * 1024 + t * 4;
        float4 v = *(const float4*)(xrow + base);
        float a = fmaxf(fmaxf(fabsf(v.x), fabsf(v.y)), fmaxf(fabsf(v.z), fabsf(v.w)));
#pragma unroll
        for (int off = 1; off < 32; off <<= 1)
            a = fmaxf(a, __shfl_xor(a, off, 64));
        const float s = fmaxf(a / QMAXF, 1e-12f);
        const float inv = 1.0f / s;      // one div per group (amortized 128x)
        float q0 = fminf(fmaxf(rintf(v.x * inv), -128.f), 127.f);
        float q1 = fminf(fmaxf(rintf(v.y * inv), -128.f), 127.f);
        float q2 = fminf(fmaxf(rintf(v.z * inv), -128.f), 127.f);
        float q3 = fminf(fmaxf(rintf(v.w * inv), -128.f), 127.f);
        char4 pk;
        pk.x = (char)(int)q0; pk.y = (char)(int)q1;
        pk.z = (char)(int)q2; pk.w = (char)(int)q3;
        *(char4*)(qrow + base) = pk;
        if ((t & 31) == 0) {
            const int g = base >> 7;
            xs_t[(size_t)g * M + m] = s;             // transposed [kb][M]
        }
    }
}

// ---------------- weight quant: per 128x128 block ----------------
__global__ __launch_bounds__(256) void weight_quant_kernel(
    const float* __restrict__ w, int8_t* __restrict__ wq, float* __restrict__ ws)
{
    const int nb = blockIdx.x >> 5;
    const int kb = blockIdx.x & 31;
    const int t  = threadIdx.x;
    const int n0 = nb * 128, k0 = kb * 128;

    float4 vals[16];
    float a = 0.f;
#pragma unroll
    for (int ii = 0; ii < 16; ++ii) {
        const int e = ii * 1024 + t * 4;
        const int row = e >> 7, col = e & 127;
        float4 v = *(const float4*)(w + (size_t)(n0 + row) * K_DIM + k0 + col);
        vals[ii] = v;
        a = fmaxf(a, fmaxf(fmaxf(fabsf(v.x), fabsf(v.y)), fmaxf(fabsf(v.z), fabsf(v.w))));
    }
#pragma unroll
    for (int off = 1; off < 64; off <<= 1)
        a = fmaxf(a, __shfl_xor(a, off, 64));
    __shared__ float wred[4];
    if ((t & 63) == 0) wred[t >> 6] = a;
    __syncthreads();
    a = fmaxf(fmaxf(wred[0], wred[1]), fmaxf(wred[2], wred[3]));
    const float s = fmaxf(a / QMAXF, 1e-12f);
    const float inv = 1.0f / s;
    if (t == 0) ws[nb * KB + kb] = s;

#pragma unroll
    for (int ii = 0; ii < 16; ++ii) {
        const int e = ii * 1024 + t * 4;
        const int row = e >> 7, col = e & 127;
        float4 v = vals[ii];
        char4 pk;
        pk.x = (char)(int)fminf(fmaxf(rintf(v.x * inv), -128.f), 127.f);
        pk.y = (char)(int)fminf(fmaxf(rintf(v.y * inv), -128.f), 127.f);
        pk.z = (char)(int)fminf(fmaxf(rintf(v.z * inv), -128.f), 127.f);
        pk.w = (char)(int)fminf(fmaxf(rintf(v.w * inv), -128.f), 127.f);
        *(char4*)(wq + (size_t)(n0 + row) * K_DIM + k0 + col) = pk;
    }
}

// ---------------- int8 GEMM v3: 256x256 tile, 8 waves, fixed vmcnt stream ----
// Fixes vs v2 (which regressed to 260us): (1) all xs_t global loads hoisted to
// phase 0 and issued BEFORE stage loads, so the compiler's wait-for-xs is a
// counted vmcnt that never drains the stage queue; (2) all 8 B fragments held
// in registers for the whole iter (no re-reads; ds_read 32->24 KB/wave/iter);
// (3) the only VM wait is at the iter boundary, where the 8 stage loads are
// the sole outstanding ops and were issued 2-4 phases (~2000 cyc) earlier.
// Quad order: (i0-3,j01) (i0-3,j23) (i4-7,j01) (i4-7,j23); A half reloaded
// at phase 2 into the same registers.
__global__ __launch_bounds__(512, 2) void gemm_kernel(
    const int8_t* __restrict__ xq, const int8_t* __restrict__ wq,
    const float* __restrict__ xs_t, const float* __restrict__ ws,
    const float* __restrict__ bias, float* __restrict__ out, int M)
{
    __shared__ __align__(16) int8_t As[2][256 * 128];
    __shared__ __align__(16) int8_t Bs[2][256 * 128];

    const int t    = threadIdx.x;
    const int lane = t & 63;
    const int wave = t >> 6;

    // XCD-aware bijective swizzle (grid size 512, divisible by 8)
    const int nwg  = gridDim.x;
    const int cpx  = nwg >> 3;
    const int bid  = blockIdx.x;
    const int tile = (bid & 7) * cpx + (bid >> 3);
    const int nbt  = tile & 15;           // N/256 = 16
    const int mbt  = tile >> 4;
    const int n0   = nbt * 256;
    const int m0   = mbt * 256;

    const int wm    = (wave >> 2) * 128;  // 2 M-halves
    const int wn    = (wave & 3) * 64;    // 4 N-quarters
    const int frow  = lane & 15;
    const int q     = lane >> 4;
    const int quad4 = q * 4;
    const int sw0   = (q ^ (frow & 7)) * 16;
    const int wsrow = ((n0 + wn) >> 7) * KB;   // wave-uniform ws column

    // staging map: LDS slot ci holds global chunk (row=ci>>3, c=(ci&7)^(row&7))
    int st_off[4];
#pragma unroll
    for (int it = 0; it < 4; ++it) {
        const int ci  = it * 512 + t;
        const int row = ci >> 3;
        const int c   = (ci & 7) ^ (row & 7);
        st_off[it] = row * K_DIM + c * 16;
    }

    float4 facc[8][4] = {};               // 128 f32 accumulators

    float bj[4];
#pragma unroll
    for (int j = 0; j < 4; ++j) bj[j] = bias[n0 + wn + j * 16 + frow];

    // ---- prologue: stage kb=0 into pair 0 ----
    {
        const int8_t* Ag = xq + (size_t)m0 * K_DIM;
        const int8_t* Bg = wq + (size_t)n0 * K_DIM;
#pragma unroll
        for (int it = 0; it < 4; ++it) {
            async_copy16(&As[0][(it * 512 + wave * 64) * 16], Ag + st_off[it]);
            async_copy16(&Bs[0][(it * 512 + wave * 64) * 16], Bg + st_off[it]);
        }
        asm volatile("s_waitcnt vmcnt(0)" ::: "memory");
        __builtin_amdgcn_s_barrier();
    }

#define PH_PRE  do { __builtin_amdgcn_s_barrier(); \
                     asm volatile("s_waitcnt lgkmcnt(0)" ::: "memory"); \
                     __builtin_amdgcn_sched_barrier(0); \
                     __builtin_amdgcn_s_setprio(1); } while (0)
#define PH_POST do { __builtin_amdgcn_s_setprio(0); \
                     __builtin_amdgcn_s_barrier(); } while (0)

#define READ_A(ihb) \
    _Pragma("unroll") \
    for (int i = 0; i < 4; ++i) { \
        const int r = wm + ((ihb) + i) * 16 + frow; \
        a0[i] = *(const v4i*)&As[cur][r * 128 + sw0]; \
        a1[i] = *(const v4i*)&As[cur][r * 128 + (sw0 ^ 64)]; \
    }
#define READ_B(jb) \
    _Pragma("unroll") \
    for (int j = 0; j < 2; ++j) { \
        const int r = wn + ((jb) + j) * 16 + frow; \
        b0[(jb) + j] = *(const v4i*)&Bs[cur][r * 128 + sw0]; \
        b1[(jb) + j] = *(const v4i*)&Bs[cur][r * 128 + (sw0 ^ 64)]; \
    }
#define MFMA_QUAD(ihb, jb) \
    _Pragma("unroll") \
    for (int i = 0; i < 4; ++i) { \
        const float s0 = xs4[(ihb) + i].x * wskb, s1 = xs4[(ihb) + i].y * wskb; \
        const float s2 = xs4[(ihb) + i].z * wskb, s3 = xs4[(ihb) + i].w * wskb; \
        _Pragma("unroll") \
        for (int j = 0; j < 2; ++j) { \
            v4i d = __builtin_amdgcn_mfma_i32_16x16x64_i8(a0[i], b0[(jb) + j], (v4i){0, 0, 0, 0}, 0, 0, 0); \
            d = __builtin_amdgcn_mfma_i32_16x16x64_i8(a1[i], b1[(jb) + j], d, 0, 0, 0); \
            float4& f = facc[(ihb) + i][(jb) + j]; \
            f.x += (float)d[0] * s0; \
            f.y += (float)d[1] * s1; \
            f.z += (float)d[2] * s2; \
            f.w += (float)d[3] * s3; \
        } \
    }

    for (int kb = 0; kb < KB; ++kb) {
        const int cur = kb & 1;
        const int nxt = cur ^ 1;
        const int pre = (kb + 1 < KB);
        const float wskb = ws[__builtin_amdgcn_readfirstlane(wsrow + kb)];
        const int8_t* Agn = xq + (size_t)m0 * K_DIM + (size_t)(kb + 1) * 128;
        const int8_t* Bgn = wq + (size_t)n0 * K_DIM + (size_t)(kb + 1) * 128;

        v4i a0[4], a1[4], b0[4], b1[4];
        float4 xs4[8];

        // ---- phase 0: reads a(i0-3), b(j0-1), ALL xs (oldest in vm queue);
        //      then stage next-A; MFMA quad(0, j01) ----
        READ_A(0)
        READ_B(0)
#pragma unroll
        for (int i = 0; i < 8; ++i)
            xs4[i] = *(const float4*)&xs_t[(size_t)kb * M + m0 + wm + i * 16 + quad4];
        __builtin_amdgcn_sched_barrier(0);   // pin: xs issued before stages
        if (pre) {
#pragma unroll
            for (int it = 0; it < 4; ++it)
                async_copy16(&As[nxt][(it * 512 + wave * 64) * 16], Agn + st_off[it]);
        }
        PH_PRE;
        MFMA_QUAD(0, 0)
        PH_POST;

        // ---- phase 1: reads b(j2-3); stage next-B; MFMA quad(0, j23) ----
        READ_B(2)
        if (pre) {
#pragma unroll
            for (int it = 0; it < 4; ++it)
                async_copy16(&Bs[nxt][(it * 512 + wave * 64) * 16], Bgn + st_off[it]);
        }
        PH_PRE;
        MFMA_QUAD(0, 2)
        PH_POST;

        // ---- phase 2: reads a(i4-7) (reuse regs); MFMA quad(4, j01) ----
        READ_A(4)
        PH_PRE;
        MFMA_QUAD(4, 0)
        PH_POST;

        // ---- phase 3: MFMA quad(4, j23); boundary wait (stages are the only
        //      outstanding VM ops, issued 2-4 phases earlier) ----
        PH_PRE;
        MFMA_QUAD(4, 2)
        __builtin_amdgcn_s_setprio(0);
        asm volatile("s_waitcnt vmcnt(0)" ::: "memory");
        __builtin_amdgcn_s_barrier();
    }

#undef PH_PRE
#undef PH_POST
#undef READ_A
#undef READ_B
#undef MFMA_QUAD

    // epilogue: C/D layout col = lane&15, row = (lane>>4)*4 + reg
#pragma unroll
    for (int i = 0; i < 8; ++i) {
#pragma unroll
        for (int r = 0; r < 4; ++r) {
            const int row = m0 + wm + i * 16 + quad4 + r;
            float* orow = out + (size_t)row * N_DIM + n0 + wn + frow;
#pragma unroll
            for (int j = 0; j < 4; ++j)
                orow[j * 16] = ((const float*)&facc[i][j])[r] + bj[j];
        }
    }
}

extern "C" void kernel_launch(void* const* d_in, const int* in_sizes, int n_in,
                              void* d_out, int out_size, void* d_ws, size_t ws_size,
                              hipStream_t stream)
{
    const float* x    = (const float*)d_in[0];
    const float* w    = (const float*)d_in[1];
    const float* bias = (const float*)d_in[2];
    float* out = (float*)d_out;
    const int M = in_sizes[0] / K_DIM;   // 8192

    int8_t* xq  = (int8_t*)d_ws;                                 // M*K
    int8_t* wqp = xq + (size_t)M * K_DIM;                        // N*K
    float*  xst = (float*)(wqp + (size_t)N_DIM * K_DIM);         // KB*M  [kb][M]
    float*  wsp = xst + (size_t)KB * M;                          // (N/128)*KB

    act_quant_kernel<<<M, 256, 0, stream>>>(x, xq, xst, M);
    weight_quant_kernel<<<(N_DIM / 128) * KB, 256, 0, stream>>>(w, wqp, wsp);
    gemm_kernel<<<(N_DIM / 256) * (M / 256), 512, 0, stream>>>(
        xq, wqp, xst, wsp, bias, out, M);
}

// Round 4
// 455.147 us; speedup vs baseline: 1.3359x; 1.3359x over previous
//
#include <hip/hip_runtime.h>
#include <stdint.h>

#define K_DIM 4096
#define N_DIM 4096
#define KB    32          // K / 128
#define QMAXF 127.0f

typedef int v4i __attribute__((ext_vector_type(4)));

__device__ __forceinline__ void async_copy16(void* lds, const void* gptr) {
    __builtin_amdgcn_global_load_lds(
        (__attribute__((address_space(1))) void*)gptr,
        (__attribute__((address_space(3))) void*)lds, 16, 0, 0);
}

// ---------------- activation quant: per (row, 128-block) ----------------
// v4: 2048 blocks, grid-stride over rows (same per-row arithmetic as the
// verified version; fewer dispatch packets in case launch-rate bound).
__global__ __launch_bounds__(256) void act_quant_kernel(
    const float* __restrict__ x, int8_t* __restrict__ xq,
    float* __restrict__ xs_t, int M)
{
    const int t = threadIdx.x;
    for (int m = blockIdx.x; m < M; m += gridDim.x) {
        const float* xrow = x + (size_t)m * K_DIM;
        int8_t* qrow = xq + (size_t)m * K_DIM;

#pragma unroll
        for (int p = 0; p < 4; ++p) {
            const int base = p * 1024 + t * 4;
            float4 v = *(const float4*)(xrow + base);
            float a = fmaxf(fmaxf(fabsf(v.x), fabsf(v.y)), fmaxf(fabsf(v.z), fabsf(v.w)));
#pragma unroll
            for (int off = 1; off < 32; off <<= 1)
                a = fmaxf(a, __shfl_xor(a, off, 64));
            const float s = fmaxf(a / QMAXF, 1e-12f);
            const float inv = 1.0f / s;
            float q0 = fminf(fmaxf(rintf(v.x * inv), -128.f), 127.f);
            float q1 = fminf(fmaxf(rintf(v.y * inv), -128.f), 127.f);
            float q2 = fminf(fmaxf(rintf(v.z * inv), -128.f), 127.f);
            float q3 = fminf(fmaxf(rintf(v.w * inv), -128.f), 127.f);
            char4 pk;
            pk.x = (char)(int)q0; pk.y = (char)(int)q1;
            pk.z = (char)(int)q2; pk.w = (char)(int)q3;
            *(char4*)(qrow + base) = pk;
            if ((t & 31) == 0) {
                const int g = base >> 7;
                xs_t[(size_t)g * M + m] = s;         // transposed [kb][M]
            }
        }
    }
}

// ---------------- weight quant: per 128x128 block ----------------
__global__ __launch_bounds__(256) void weight_quant_kernel(
    const float* __restrict__ w, int8_t* __restrict__ wq, float* __restrict__ ws)
{
    const int nb = blockIdx.x >> 5;
    const int kb = blockIdx.x & 31;
    const int t  = threadIdx.x;
    const int n0 = nb * 128, k0 = kb * 128;

    float4 vals[16];
    float a = 0.f;
#pragma unroll
    for (int ii = 0; ii < 16; ++ii) {
        const int e = ii * 1024 + t * 4;
        const int row = e >> 7, col = e & 127;
        float4 v = *(const float4*)(w + (size_t)(n0 + row) * K_DIM + k0 + col);
        vals[ii] = v;
        a = fmaxf(a, fmaxf(fmaxf(fabsf(v.x), fabsf(v.y)), fmaxf(fabsf(v.z), fabsf(v.w))));
    }
#pragma unroll
    for (int off = 1; off < 64; off <<= 1)
        a = fmaxf(a, __shfl_xor(a, off, 64));
    __shared__ float wred[4];
    if ((t & 63) == 0) wred[t >> 6] = a;
    __syncthreads();
    a = fmaxf(fmaxf(wred[0], wred[1]), fmaxf(wred[2], wred[3]));
    const float s = fmaxf(a / QMAXF, 1e-12f);
    const float inv = 1.0f / s;
    if (t == 0) ws[nb * KB + kb] = s;

#pragma unroll
    for (int ii = 0; ii < 16; ++ii) {
        const int e = ii * 1024 + t * 4;
        const int row = e >> 7, col = e & 127;
        float4 v = vals[ii];
        char4 pk;
        pk.x = (char)(int)fminf(fmaxf(rintf(v.x * inv), -128.f), 127.f);
        pk.y = (char)(int)fminf(fmaxf(rintf(v.y * inv), -128.f), 127.f);
        pk.z = (char)(int)fminf(fmaxf(rintf(v.z * inv), -128.f), 127.f);
        pk.w = (char)(int)fminf(fmaxf(rintf(v.w * inv), -128.f), 127.f);
        *(char4*)(wq + (size_t)(n0 + row) * K_DIM + k0 + col) = pk;
    }
}

// ---------------- int8 GEMM v4: 256x256, 8 waves, LDS-staged scales --------
// v3 spilled (WRITE_SIZE 306MB): xs4[8] float4 held across all phases pushed
// the wave past the 256-reg cap (128 acc + ~145 arch). v4 keeps v3's clean
// vm-queue (no mid-loop global scalar loads) but moves activation scales
// through a double-buffered 1KB LDS strip staged by global_load_lds (wave 0),
// drained by the same iter-boundary vmcnt(0) as the A/B stages. Per-phase the
// scales are 4 short-lived ds_read_b128 (broadcast within 16-lane groups,
// conflict-free), covered by the per-phase lgkmcnt(0). bias load moved to
// epilogue. Hot-loop arch regs ~115 + 128 acc -> fits, no scratch.
__global__ __launch_bounds__(512, 2) void gemm_kernel(
    const int8_t* __restrict__ xq, const int8_t* __restrict__ wq,
    const float* __restrict__ xs_t, const float* __restrict__ ws,
    const float* __restrict__ bias, float* __restrict__ out, int M)
{
    __shared__ __align__(16) int8_t As[2][256 * 128];
    __shared__ __align__(16) int8_t Bs[2][256 * 128];
    __shared__ __align__(16) float  xs_lds[2][256];

    const int t    = threadIdx.x;
    const int lane = t & 63;
    const int wave = t >> 6;

    // XCD-aware bijective swizzle (grid size 512, divisible by 8)
    const int nwg  = gridDim.x;
    const int cpx  = nwg >> 3;
    const int bid  = blockIdx.x;
    const int tile = (bid & 7) * cpx + (bid >> 3);
    const int nbt  = tile & 15;           // N/256 = 16
    const int mbt  = tile >> 4;
    const int n0   = nbt * 256;
    const int m0   = mbt * 256;

    const int wm    = (wave >> 2) * 128;  // 2 M-halves
    const int wn    = (wave & 3) * 64;    // 4 N-quarters
    const int frow  = lane & 15;
    const int q     = lane >> 4;
    const int quad4 = q * 4;
    const int sw0   = (q ^ (frow & 7)) * 16;
    const int wsrow = ((n0 + wn) >> 7) * KB;   // wave-uniform ws column

    // staging map: LDS slot ci holds global chunk (row=ci>>3, c=(ci&7)^(row&7))
    int st_off[4];
#pragma unroll
    for (int it = 0; it < 4; ++it) {
        const int ci  = it * 512 + t;
        const int row = ci >> 3;
        const int c   = (ci & 7) ^ (row & 7);
        st_off[it] = row * K_DIM + c * 16;
    }

    const int8_t* Abase = xq + (size_t)m0 * K_DIM;
    const int8_t* Bbase = wq + (size_t)n0 * K_DIM;

    float4 facc[8][4] = {};               // 128 f32 accumulators

    // ---- prologue: stage kb=0 (A, B, xs strip) into buffer 0 ----
    {
#pragma unroll
        for (int it = 0; it < 4; ++it) {
            async_copy16(&As[0][(it * 512 + wave * 64) * 16], Abase + st_off[it]);
            async_copy16(&Bs[0][(it * 512 + wave * 64) * 16], Bbase + st_off[it]);
        }
        if (t < 64)
            async_copy16(&xs_lds[0][0], xs_t + m0 + t * 4);
        asm volatile("s_waitcnt vmcnt(0)" ::: "memory");
        __builtin_amdgcn_s_barrier();
    }

#define PH_PRE  do { __builtin_amdgcn_s_barrier(); \
                     asm volatile("s_waitcnt lgkmcnt(0)" ::: "memory"); \
                     __builtin_amdgcn_sched_barrier(0); \
                     __builtin_amdgcn_s_setprio(1); } while (0)
#define PH_POST do { __builtin_amdgcn_s_setprio(0); \
                     __builtin_amdgcn_s_barrier(); } while (0)

#define READ_A(ihb) \
    _Pragma("unroll") \
    for (int i = 0; i < 4; ++i) { \
        const int r = wm + ((ihb) + i) * 16 + frow; \
        a0[i] = *(const v4i*)&As[cur][r * 128 + sw0]; \
        a1[i] = *(const v4i*)&As[cur][r * 128 + (sw0 ^ 64)]; \
    }
#define READ_B(jb) \
    _Pragma("unroll") \
    for (int j = 0; j < 2; ++j) { \
        const int r = wn + ((jb) + j) * 16 + frow; \
        b0[(jb) + j] = *(const v4i*)&Bs[cur][r * 128 + sw0]; \
        b1[(jb) + j] = *(const v4i*)&Bs[cur][r * 128 + (sw0 ^ 64)]; \
    }
#define READ_XS(ihb) \
    _Pragma("unroll") \
    for (int i = 0; i < 4; ++i) \
        xs4[i] = *(const float4*)&xs_lds[cur][wm + ((ihb) + i) * 16 + quad4];
#define MFMA_QUAD(ihb, jb) \
    _Pragma("unroll") \
    for (int i = 0; i < 4; ++i) { \
        const float s0 = xs4[i].x * wskb, s1 = xs4[i].y * wskb; \
        const float s2 = xs4[i].z * wskb, s3 = xs4[i].w * wskb; \
        _Pragma("unroll") \
        for (int j = 0; j < 2; ++j) { \
            v4i d = __builtin_amdgcn_mfma_i32_16x16x64_i8(a0[i], b0[(jb) + j], (v4i){0, 0, 0, 0}, 0, 0, 0); \
            d = __builtin_amdgcn_mfma_i32_16x16x64_i8(a1[i], b1[(jb) + j], d, 0, 0, 0); \
            float4& f = facc[(ihb) + i][(jb) + j]; \
            f.x += (float)d[0] * s0; \
            f.y += (float)d[1] * s1; \
            f.z += (float)d[2] * s2; \
            f.w += (float)d[3] * s3; \
        } \
    }

    for (int kb = 0; kb < KB; ++kb) {
        const int cur = kb & 1;
        const int nxt = cur ^ 1;
        const int pre = (kb + 1 < KB);
        const float wskb = ws[__builtin_amdgcn_readfirstlane(wsrow + kb)];
        const int8_t* Agn = Abase + (size_t)(kb + 1) * 128;
        const int8_t* Bgn = Bbase + (size_t)(kb + 1) * 128;

        v4i a0[4], a1[4], b0[4], b1[4];
        float4 xs4[4];

        // ---- phase 0: ds-read a(i0-3), b(j0-1), xs(lo); stage next A + xs ----
        READ_A(0)
        READ_B(0)
        READ_XS(0)
        if (pre) {
#pragma unroll
            for (int it = 0; it < 4; ++it)
                async_copy16(&As[nxt][(it * 512 + wave * 64) * 16], Agn + st_off[it]);
            if (t < 64)
                async_copy16(&xs_lds[nxt][0], xs_t + (size_t)(kb + 1) * M + m0 + t * 4);
        }
        PH_PRE;
        MFMA_QUAD(0, 0)
        PH_POST;

        // ---- phase 1: ds-read b(j2-3); stage next B ----
        READ_B(2)
        if (pre) {
#pragma unroll
            for (int it = 0; it < 4; ++it)
                async_copy16(&Bs[nxt][(it * 512 + wave * 64) * 16], Bgn + st_off[it]);
        }
        PH_PRE;
        MFMA_QUAD(0, 2)
        PH_POST;

        // ---- phase 2: ds-read a(i4-7) (reuse regs), xs(hi) ----
        READ_A(4)
        READ_XS(4)
        PH_PRE;
        MFMA_QUAD(4, 0)
        PH_POST;

        // ---- phase 3: MFMA only; boundary wait (stages are the sole
        //      outstanding VM ops, issued 2-4 phases earlier) ----
        PH_PRE;
        MFMA_QUAD(4, 2)
        __builtin_amdgcn_s_setprio(0);
        asm volatile("s_waitcnt vmcnt(0)" ::: "memory");
        __builtin_amdgcn_s_barrier();
    }

#undef PH_PRE
#undef PH_POST
#undef READ_A
#undef READ_B
#undef READ_XS
#undef MFMA_QUAD

    // epilogue: C/D layout col = lane&15, row = (lane>>4)*4 + reg
    float bj[4];
#pragma unroll
    for (int j = 0; j < 4; ++j) bj[j] = bias[n0 + wn + j * 16 + frow];
#pragma unroll
    for (int i = 0; i < 8; ++i) {
#pragma unroll
        for (int r = 0; r < 4; ++r) {
            const int row = m0 + wm + i * 16 + quad4 + r;
            float* orow = out + (size_t)row * N_DIM + n0 + wn + frow;
#pragma unroll
            for (int j = 0; j < 4; ++j)
                orow[j * 16] = ((const float*)&facc[i][j])[r] + bj[j];
        }
    }
}

extern "C" void kernel_launch(void* const* d_in, const int* in_sizes, int n_in,
                              void* d_out, int out_size, void* d_ws, size_t ws_size,
                              hipStream_t stream)
{
    const float* x    = (const float*)d_in[0];
    const float* w    = (const float*)d_in[1];
    const float* bias = (const float*)d_in[2];
    float* out = (float*)d_out;
    const int M = in_sizes[0] / K_DIM;   // 8192

    int8_t* xq  = (int8_t*)d_ws;                                 // M*K
    int8_t* wqp = xq + (size_t)M * K_DIM;                        // N*K
    float*  xst = (float*)(wqp + (size_t)N_DIM * K_DIM);         // KB*M  [kb][M]
    float*  wsp = xst + (size_t)KB * M;                          // (N/128)*KB

    act_quant_kernel<<<2048, 256, 0, stream>>>(x, xq, xst, M);
    weight_quant_kernel<<<(N_DIM / 128) * KB, 256, 0, stream>>>(w, wqp, wsp);
    gemm_kernel<<<(N_DIM / 256) * (M / 256), 512, 0, stream>>>(
        xq, wqp, xst, wsp, bias, out, M);
}